// Round 7
// baseline (329.225 us; speedup 1.0000x reference)
//
#include <hip/hip_runtime.h>
#include <hip/hip_bf16.h>
#include <stdint.h>

// ---------- types ----------
typedef __attribute__((ext_vector_type(8))) __bf16 bf16x8;
typedef __attribute__((ext_vector_type(4))) float f32x4;
typedef __attribute__((ext_vector_type(8))) unsigned short ushort8;

typedef const void __attribute__((address_space(1))) gv_t;
typedef void __attribute__((address_space(3))) lv_t;

#define GL16(g, l) __builtin_amdgcn_global_load_lds((gv_t*)(g), (lv_t*)(l), 16, 0, 0)

__device__ __forceinline__ unsigned short f2bf(float f) {
    unsigned int u = __float_as_uint(f);
    u += 0x7fffu + ((u >> 16) & 1u);
    return (unsigned short)(u >> 16);
}

// ---------- kernel 1: per-group int4 quant-dequant of W -> bf16 bits ----------
__global__ void __launch_bounds__(256) qdq_weight(const float* __restrict__ w,
                                                  unsigned short* __restrict__ wb,
                                                  int n_groups) {
    int g = blockIdx.x * 256 + threadIdx.x;
    if (g >= n_groups) return;
    const float4* p = (const float4*)w + (size_t)g * 2;
    float4 v0 = p[0], v1 = p[1];
    float t[8] = {v0.x, v0.y, v0.z, v0.w, v1.x, v1.y, v1.z, v1.w};
    float amax = 0.0f;
#pragma unroll
    for (int j = 0; j < 8; ++j) amax = fmaxf(amax, fabsf(t[j]));
    float scale = fmaxf(amax / 7.0f, 1e-8f);
    ushort8 o;
#pragma unroll
    for (int j = 0; j < 8; ++j) {
        float q = rintf(t[j] / scale);
        q = fminf(fmaxf(q, -7.0f), 7.0f);
        o[j] = f2bf(q * scale);
    }
    *((ushort8*)wb + g) = o;
}

// ---------- kernel 2: f32 -> bf16 cast of x ----------
__global__ void __launch_bounds__(256) cvt_bf16(const float* __restrict__ x,
                                                unsigned short* __restrict__ xb,
                                                int n8) {
    int i = blockIdx.x * 256 + threadIdx.x;
    if (i >= n8) return;
    const float4* p = (const float4*)x + (size_t)i * 2;
    float4 v0 = p[0], v1 = p[1];
    ushort8 o;
    o[0] = f2bf(v0.x); o[1] = f2bf(v0.y); o[2] = f2bf(v0.z); o[3] = f2bf(v0.w);
    o[4] = f2bf(v1.x); o[5] = f2bf(v1.y); o[6] = f2bf(v1.z); o[7] = f2bf(v1.w);
    *((ushort8*)xb + i) = o;
}

// ---------- kernel 3: 128x256 4-wave, BK=32, 2-blocks/CU bf16 GEMM ----------
// Block = 256 threads (4 waves, 1x4 in N; per-wave 128x64 output, acc[8][4]).
// LDS 48 KB -> 2 independent barrier domains per CU: one block's MFMA phase
// overlaps the other's read-drain/stage phase (cross-block pipelining).
// Swizzle: 16B chunk c stored at c ^ ((row>>1)&3); BK=32 -> 4 chunks/row;
// 64-lane reads spread 8 lanes/bank-quad uniformly (balanced, conflict-free).
#define BM 128
#define BN 256
#define BK 32

// one phase's MFMA cluster: all 8 m-frags x 2 n-frags (q selects n-pair), K=32
#define MFMA_PH(q)                                                             \
    __builtin_amdgcn_s_setprio(1);                                             \
    _Pragma("unroll")                                                          \
    for (int mi = 0; mi < 8; ++mi)                                             \
        _Pragma("unroll")                                                      \
        for (int nn = 0; nn < 2; ++nn)                                         \
            acc[mi][(q) * 2 + nn] =                                            \
                __builtin_amdgcn_mfma_f32_16x16x32_bf16(                       \
                    af[mi], bf[(q) * 2 + nn], acc[mi][(q) * 2 + nn], 0, 0, 0); \
    __builtin_amdgcn_s_setprio(0);

// stage A tile (128 rows x 32) -> buf b: 2 rounds of 64 rows
#define STAGE_A(b, kk)                                                         \
    {                                                                          \
        _Pragma("unroll")                                                      \
        for (int j = 0; j < 2; ++j)                                            \
            GL16(gA + (size_t)(j * 64 + srow4) * K + (kk) + schunk2,           \
                 &sA[b][(j * 64 + w * 16) * BK]);                              \
    }
// stage B rounds j0..j0+1 (rows j*64..) -> buf b
#define STAGE_B2(b, kk, j0)                                                    \
    {                                                                          \
        _Pragma("unroll")                                                      \
        for (int j = (j0); j < (j0) + 2; ++j)                                  \
            GL16(gB + (size_t)(j * 64 + srow4) * K + (kk) + schunk2,           \
                 &sB[b][(j * 64 + w * 16) * BK]);                              \
    }

#define READ_A(b)                                                              \
    _Pragma("unroll")                                                          \
    for (int mi = 0; mi < 8; ++mi)                                             \
        af[mi] = *(const bf16x8*)&sA[b][(mi * 16 + lr) * BK + ce];
#define READ_B2(b, q)                                                          \
    _Pragma("unroll")                                                          \
    for (int nn = 0; nn < 2; ++nn)                                             \
        bf[(q) * 2 + nn] =                                                     \
            *(const bf16x8*)&sB[b][(bcol + ((q) * 2 + nn) * 16 + lr) * BK + ce];

#define BAR_()     asm volatile("s_barrier" ::: "memory")
#define VM0_()     asm volatile("s_waitcnt vmcnt(0)" ::: "memory")
#define LGKM0_()   asm volatile("s_waitcnt lgkmcnt(0)" ::: "memory")
#define SCHEDBAR() __builtin_amdgcn_sched_barrier(0)

__global__ void __launch_bounds__(256, 2)
gemm128(const unsigned short* __restrict__ A,   // [M][K] bf16 bits (x)
        const unsigned short* __restrict__ B,   // [N][K] bf16 bits (w_deq)
        const float* __restrict__ bias,
        float* __restrict__ C,
        int M, int N, int K) {
    __shared__ unsigned short sA[2][BM * BK];   // 2 x 8 KB
    __shared__ unsigned short sB[2][BN * BK];   // 2 x 16 KB  (48 KB total)

    const int t  = threadIdx.x;
    const int w  = t >> 6;        // wave 0..3 (N-split)
    const int ln = t & 63;
    const int lr = ln & 15;
    const int lk = ln >> 4;
    const int bcol = w * 64;      // B slot base for this wave

    // T1: bijective XCD swizzle (gridDim.x = 1024, % 8 == 0)
    const int nbn = N / BN;
    const int bid = blockIdx.x;
    const int swz = ((int)gridDim.x & 7) ? bid
                  : ((bid & 7) * ((int)gridDim.x >> 3) + (bid >> 3));
    const int m0 = (swz / nbn) * BM;
    const int n0 = (swz % nbn) * BN;

    const unsigned short* gA = A + (size_t)m0 * K;
    const unsigned short* gB = B + (size_t)n0 * K;

    // staging coords: lane covers (row = base + ln>>2, chunk = ln&3),
    // source chunk pre-swizzled by ((row>>1)&3) == ((ln>>3)&3)
    const int srow4   = w * 16 + (ln >> 2);
    const int schunk2 = (((ln & 3) ^ ((ln >> 3) & 3)) << 3);   // elements

    // read chunk offset: logical chunk lk stored at lk ^ ((row>>1)&3);
    // row = base16 + lr -> (row>>1)&3 == ((lr>>1)&3)
    const int ce = ((lk ^ ((lr >> 1) & 3)) << 3);              // elements

    f32x4 acc[8][4];
#pragma unroll
    for (int i = 0; i < 8; ++i)
#pragma unroll
        for (int j = 0; j < 4; ++j)
            acc[i][j] = (f32x4)(0.0f);

    bf16x8 af[8], bf[4];

    const int NT = K / BK;   // 128, even

    // prologue: tile 0 -> buf 0 (A: 2 loads, B: 4 loads per thread)
    STAGE_A(0, 0);
    STAGE_B2(0, 0, 0);
    STAGE_B2(0, 0, 2);
    VM0_();
    BAR_();

    for (int it = 0; it < NT / 2; ++it) {
        const int t0  = 2 * it;
        const int kn1 = (t0 + 1) * BK;          // always < K
        const int kn2 = (t0 + 2) * BK;
        const bool st2 = (t0 + 2 < NT);

        // ---- tile t0: read buf0, stage tile t0+1 -> buf1 ----
        // ph1: A(8)+B01(2) reads; stage A-next + B-next rows 0..127; Q-left
        READ_A(0); READ_B2(0, 0);
        STAGE_A(1, kn1); STAGE_B2(1, kn1, 0);
        BAR_(); LGKM0_(); SCHEDBAR();
        MFMA_PH(0);
        BAR_();
        // ph2: B23(2) reads; stage B-next rows 128..255; Q-right; drain
        READ_B2(0, 1);
        STAGE_B2(1, kn1, 2);
        BAR_(); LGKM0_(); SCHEDBAR();
        MFMA_PH(1);
        VM0_();
        BAR_();

        // ---- tile t0+1: read buf1, stage tile t0+2 -> buf0 ----
        READ_A(1); READ_B2(1, 0);
        if (st2) { STAGE_A(0, kn2); STAGE_B2(0, kn2, 0); }
        BAR_(); LGKM0_(); SCHEDBAR();
        MFMA_PH(0);
        BAR_();

        READ_B2(1, 1);
        if (st2) STAGE_B2(0, kn2, 2);
        BAR_(); LGKM0_(); SCHEDBAR();
        MFMA_PH(1);
        VM0_();
        BAR_();
    }

    // epilogue: C/D layout col = lane&15, row = (lane>>4)*4 + reg
#pragma unroll
    for (int j = 0; j < 4; ++j) {
        const int n = n0 + bcol + j * 16 + lr;
        const float bv = bias[n];
#pragma unroll
        for (int i = 0; i < 8; ++i) {
            const int m = m0 + i * 16 + lk * 4;
            f32x4 v = acc[i][j];
            C[(size_t)(m + 0) * N + n] = v[0] + bv;
            C[(size_t)(m + 1) * N + n] = v[1] + bv;
            C[(size_t)(m + 2) * N + n] = v[2] + bv;
            C[(size_t)(m + 3) * N + n] = v[3] + bv;
        }
    }
}

// ---------- launcher ----------
extern "C" void kernel_launch(void* const* d_in, const int* in_sizes, int n_in,
                              void* d_out, int out_size, void* d_ws, size_t ws_size,
                              hipStream_t stream) {
    const float* x    = (const float*)d_in[0];
    const float* wgt  = (const float*)d_in[1];
    const float* bias = (const float*)d_in[2];
    float* out        = (float*)d_out;

    const int dout = in_sizes[2];            // 4096
    const int din  = in_sizes[1] / dout;     // 4096
    const int M    = in_sizes[0] / din;      // 8192
    const int N    = dout, K = din;

    unsigned short* xb = (unsigned short*)d_ws;          // [M][K] bf16 bits
    unsigned short* wb = xb + (size_t)M * K;             // [N][K] bf16 bits

    const int ng_w = (N * K) / 8;
    qdq_weight<<<(ng_w + 255) / 256, 256, 0, stream>>>(wgt, wb, ng_w);

    const int n8_x = (M * K) / 8;
    cvt_bf16<<<(n8_x + 255) / 256, 256, 0, stream>>>(x, xb, n8_x);

    const int nwg = (M / BM) * (N / BN);     // 64 * 16 = 1024, % 8 == 0
    gemm128<<<nwg, 256, 0, stream>>>(xb, wb, bias, out, M, N, K);
}